// Round 1
// baseline (2384.160 us; speedup 1.0000x reference)
//
#include <hip/hip_runtime.h>
#include <hip/hip_bf16.h>

#define BS 4
#define LL 1024
#define DD 768
#define HH 12
#define NE 42
#define NM 8
#define KK 97
#define PPAIR 128
#define FF 256
#define RR 256
#define NPAIR (BS*PPAIR)     // 512
#define MROWS (BS*NE*KK)     // 16296

__device__ __forceinline__ float fast_tanh(float x){
  x = fminf(fmaxf(x, -15.f), 15.f);
  float e = __expf(2.f*x);
  return 1.f - 2.f/(e + 1.f);
}

// ---------------- K1: emb[b,e,m,:] = seq[b,pos,:] * mask ----------------
__global__ void k_emb(const float* __restrict__ seq, const int* __restrict__ mpos,
                      const float* __restrict__ mask, float* __restrict__ emb){
  int idx = blockIdx.x;            // (b*NE+e)*NM+m
  int t = threadIdx.x;
  int b = idx / (NE*NM);
  float mk = mask[idx];
  int pos = mpos[idx] + 1;
  pos = min(max(pos, 0), LL-1);
  const float* src = seq + ((size_t)b*LL + pos)*DD;
  float* dst = emb + (size_t)idx*DD;
  for (int dd = t; dd < DD; dd += 256) dst[dd] = mk * src[dd];
}

// ------------- K2: entity_as[b,e,h,l] = sum_m mask*att[b,h,pos,l]/cnt -------------
__global__ void k_entity_as(const float* __restrict__ att, const int* __restrict__ mpos,
                            const float* __restrict__ mask, float* __restrict__ eas){
  int idx = blockIdx.x;            // (b*NE+e)*HH + hh
  int hh = idx % HH; int be = idx / HH;
  int b = be / NE;
  int t = threadIdx.x;
  float cnt = 0.f;
  for (int m=0;m<NM;m++) cnt += mask[be*NM+m];
  float inv = 1.f / fmaxf(cnt, 1.f);
  float acc[4] = {0.f,0.f,0.f,0.f};
  for (int m=0;m<NM;m++){
    float mk = mask[be*NM+m];
    if (mk != 0.f){
      int pos = min(max(mpos[be*NM+m]+1,0), LL-1);
      const float* row = att + (((size_t)b*HH + hh)*LL + pos)*LL;
      acc[0] += mk*row[t]; acc[1] += mk*row[t+256];
      acc[2] += mk*row[t+512]; acc[3] += mk*row[t+768];
    }
  }
  float* dst = eas + (size_t)idx*LL;
  dst[t]=acc[0]*inv; dst[t+256]=acc[1]*inv; dst[t+512]=acc[2]*inv; dst[t+768]=acc[3]*inv;
}

// ------------- K3a: tbuf[b,e,m,r] = tanh(emb . Wattn[:,r] + battn[r]) -------------
__global__ void k_score1(const float* __restrict__ emb, const float* __restrict__ Wattn,
                         const float* __restrict__ battn, float* __restrict__ tbuf){
  int idx = blockIdx.x; int t = threadIdx.x;  // 256 threads, r = t
  __shared__ float es[DD];
  es[t]       = emb[(size_t)idx*DD + t];
  es[t+256]   = emb[(size_t)idx*DD + t + 256];
  es[t+512]   = emb[(size_t)idx*DD + t + 512];
  __syncthreads();
  float acc = battn[t];
  for (int dd=0; dd<DD; dd++) acc += es[dd]*Wattn[dd*RR + t];
  tbuf[(size_t)idx*RR + t] = fast_tanh(acc);
}

// ------------- K3b: scores + masked softmax over mentions -> w[b,e,m,k] -------------
__global__ void k_scores(const float* __restrict__ tbuf, const float* __restrict__ an,
                         const float* __restrict__ mask, float* __restrict__ w){
  int be = blockIdx.x; int t = threadIdx.x;   // 128 threads
  __shared__ float ts_[NM*RR];                // 8 KB
  __shared__ float an_s[64*98];               // 25 KB chunk of attn_net^T
  for (int i=t; i<NM*RR; i+=128) ts_[i] = tbuf[(size_t)be*NM*RR + i];
  float acc[NM];
  #pragma unroll
  for (int m=0;m<NM;m++) acc[m] = 0.f;
  for (int rc=0; rc<RR; rc+=64){
    __syncthreads();
    for (int i=t; i<KK*64; i+=128){
      int kq = i >> 6, r = i & 63;
      an_s[r*98 + kq] = an[kq*RR + rc + r];   // coalesced read, transposed store
    }
    __syncthreads();
    if (t < KK){
      for (int m=0;m<NM;m++){
        float a = 0.f;
        for (int r=0;r<64;r++) a += ts_[m*RR + rc + r]*an_s[r*98 + t];
        acc[m] += a;
      }
    }
  }
  if (t < KK){
    float s[NM];
    #pragma unroll
    for (int m=0;m<NM;m++){
      float mk = mask[be*NM+m];
      s[m] = acc[m] + (1.f - mk)*(-1e6f);
    }
    float mx = s[0];
    #pragma unroll
    for (int m=1;m<NM;m++) mx = fmaxf(mx, s[m]);
    float sum = 0.f; float e[NM];
    #pragma unroll
    for (int m=0;m<NM;m++){ e[m] = __expf(s[m]-mx); sum += e[m]; }
    float invs = 1.f/sum;
    #pragma unroll
    for (int m=0;m<NM;m++) w[((size_t)be*NM+m)*KK + t] = e[m]*invs;
  }
}

// ------------- K4: entity_es[b,e,k,:] = sum_m w[b,e,m,k]*emb[b,e,m,:] -------------
__global__ void k_entity_es(const float* __restrict__ emb, const float* __restrict__ w,
                            float* __restrict__ ees){
  int be = blockIdx.x; int t = threadIdx.x;
  __shared__ float es[NM*DD];    // 24 KB
  __shared__ float ws[NM*KK];
  for (int i = t; i < NM*DD; i += 256) es[i] = emb[(size_t)be*NM*DD + i];
  for (int i = t; i < NM*KK; i += 256) ws[i] = w[(size_t)be*NM*KK + i];
  __syncthreads();
  for (int k=0;k<KK;k++){
    float* dst = ees + ((size_t)be*KK + k)*DD;
    #pragma unroll
    for (int i=0;i<3;i++){
      int dd = t + i*256;
      float a = 0.f;
      #pragma unroll
      for (int m=0;m<NM;m++) a += ws[m*KK + k]*es[m*DD + dd];
      dst[dd] = a;
    }
  }
}

// ------------- K6: seqlin[b,l,c] = seq[b,l,:] . Wlin[:,c] -------------
__global__ void k_seqlin(const float* __restrict__ seq, const float* __restrict__ Wlin,
                         float* __restrict__ sl){
  int bl = blockIdx.x; int t = threadIdx.x;
  const float* row = seq + (size_t)bl*DD;
  float a[3] = {0.f,0.f,0.f};
  for (int dd=t; dd<DD; dd+=256){
    float v = row[dd];
    a[0] += v*Wlin[dd*3+0]; a[1] += v*Wlin[dd*3+1]; a[2] += v*Wlin[dd*3+2];
  }
  __shared__ float red[256];
  float res[3];
  for (int c=0;c<3;c++){
    red[t] = a[c]; __syncthreads();
    for (int off=128; off>0; off>>=1){ if (t<off) red[t]+=red[t+off]; __syncthreads(); }
    res[c] = red[0]; __syncthreads();
  }
  if (t==0){ sl[bl*3+0]=res[0]; sl[bl*3+1]=res[1]; sl[bl*3+2]=res[2]; }
}

// ------------- K5: fused ht einsum + row-normalize + x = htn@seqlin + blin -------------
__global__ void k_ht_x(const float* __restrict__ eas, const float* __restrict__ sl,
                       const float* __restrict__ blin, float* __restrict__ x){
  int idx = blockIdx.x;            // (b*NE+i)*NE + j
  int j = idx % NE; int i = (idx/NE)%NE; int b = idx/(NE*NE);
  int t = threadIdx.x;
  const float* ai = eas + ((size_t)(b*NE+i))*HH*LL;
  const float* aj = eas + ((size_t)(b*NE+j))*HH*LL;
  float v[4];
  #pragma unroll
  for (int it=0; it<4; it++){
    int l = t + it*256;
    float acc=0.f;
    #pragma unroll
    for (int hh2=0; hh2<HH; hh2++) acc += ai[hh2*LL + l]*aj[hh2*LL + l];
    v[it] = acc * (1.f/HH);
  }
  __shared__ float red[256];
  red[t] = v[0]+v[1]+v[2]+v[3]; __syncthreads();
  for (int off=128; off>0; off>>=1){ if (t<off) red[t]+=red[t+off]; __syncthreads(); }
  float inv = 1.f/(red[0] + 1e-5f);
  __syncthreads();
  float xa[3]={0.f,0.f,0.f};
  #pragma unroll
  for (int it=0; it<4; it++){
    int l = t + it*256;
    float wv = v[it]*inv;
    const float* s3 = sl + ((size_t)b*LL + l)*3;
    xa[0]+=wv*s3[0]; xa[1]+=wv*s3[1]; xa[2]+=wv*s3[2];
  }
  for (int c=0;c<3;c++){
    red[t]=xa[c]; __syncthreads();
    for (int off=128; off>0; off>>=1){ if (t<off) red[t]+=red[t+off]; __syncthreads(); }
    if (t==0) x[(size_t)idx*3+c] = red[0] + blin[c];
    __syncthreads();
  }
}

// ------------- K8: 3x3x(3->256) conv + relu evaluated only at gathered pairs -------------
__global__ void k_conv_pairs(const float* __restrict__ x, const int* __restrict__ pairs,
                             const float* __restrict__ Wseg, const float* __restrict__ bseg,
                             float* __restrict__ htss){
  int n = blockIdx.x; int t = threadIdx.x;   // t = f channel
  int b = n / PPAIR;
  int hi = pairs[n*2+0], ti = pairs[n*2+1];
  __shared__ float xs[27];
  if (t < 27){
    int di = t/9, dj = (t/3)%3, ci = t%3;
    int ii = hi + di - 1, jj = ti + dj - 1;
    float v = 0.f;
    if (ii>=0 && ii<NE && jj>=0 && jj<NE) v = x[(((size_t)b*NE+ii)*NE+jj)*3 + ci];
    xs[t] = v;
  }
  __syncthreads();
  float acc = bseg[t];
  #pragma unroll
  for (int tap=0; tap<27; tap++) acc += xs[tap]*Wseg[tap*FF + t];
  htss[(size_t)n*FF + t] = fmaxf(acc, 0.f);
}

// ------------- K9: pairh[n,:] = htss[n,:] @ W[768:1024,:] + bias -------------
__global__ void k_pair_proj(const float* __restrict__ htss, const float* __restrict__ Wb,
                            const float* __restrict__ bias, float* __restrict__ outp){
  int n = blockIdx.x; int t = threadIdx.x;
  __shared__ float hs_s[FF];
  hs_s[t] = htss[(size_t)n*FF + t];
  __syncthreads();
  float a0 = bias[t], a1 = bias[t+256], a2 = bias[t+512];
  for (int r=0;r<FF;r++){
    float hv = hs_s[r];
    const float* wr = Wb + (size_t)r*DD;
    a0 += hv*wr[t]; a1 += hv*wr[t+256]; a2 += hv*wr[t+512];
  }
  float* dst = outp + (size_t)n*DD;
  dst[t]=a0; dst[t+256]=a1; dst[t+512]=a2;
}

// ------------- K10: C[M,768] = A[M,768] @ B[768,768]  (fp32 tiled) -------------
__global__ __launch_bounds__(256) void k_gemm768(const float* __restrict__ A,
    const float* __restrict__ B, float* __restrict__ C, int M){
  __shared__ __align__(16) float As[16][68];
  __shared__ __align__(16) float Bs[16][68];
  int bx = blockIdx.x % 12, by = blockIdx.x / 12;
  int t = threadIdx.x; int tx = t & 15, ty = t >> 4;
  int m0 = by*64, n0 = bx*64;
  int arow = t >> 2, acol = (t & 3)*4;
  int brow = t >> 4, bcol = (t & 15)*4;
  float c[4][4] = {};
  for (int kt=0; kt<768; kt+=16){
    float4 av = make_float4(0.f,0.f,0.f,0.f);
    if (m0 + arow < M) av = *(const float4*)(A + (size_t)(m0+arow)*768 + kt + acol);
    As[acol+0][arow]=av.x; As[acol+1][arow]=av.y; As[acol+2][arow]=av.z; As[acol+3][arow]=av.w;
    float4 bv = *(const float4*)(B + (size_t)(kt+brow)*768 + n0 + bcol);
    *(float4*)&Bs[brow][bcol] = bv;
    __syncthreads();
    #pragma unroll
    for (int kk=0;kk<16;kk++){
      float4 a4 = *(const float4*)&As[kk][ty*4];
      float4 b4 = *(const float4*)&Bs[kk][tx*4];
      float ar[4]={a4.x,a4.y,a4.z,a4.w}, br[4]={b4.x,b4.y,b4.z,b4.w};
      #pragma unroll
      for (int i2=0;i2<4;i2++)
        #pragma unroll
        for (int j2=0;j2<4;j2++) c[i2][j2] += ar[i2]*br[j2];
    }
    __syncthreads();
  }
  #pragma unroll
  for (int i2=0;i2<4;i2++){
    int row = m0 + ty*4 + i2;
    if (row < M){
      float4 o = make_float4(c[i2][0],c[i2][1],c[i2][2],c[i2][3]);
      *(float4*)(C + (size_t)row*768 + n0 + tx*4) = o;
    }
  }
}

// ------------- K11: logits[n,k] = tanh(Eh+ph) @ B_k @ tanh(Et+pt) + bias -------------
__global__ __launch_bounds__(256) void k_bilinear(
    const float* __restrict__ Eh, const float* __restrict__ Et,
    const float* __restrict__ ph, const float* __restrict__ pt_,
    const float* __restrict__ B, const float* __restrict__ bias,
    const int* __restrict__ pairs, float* __restrict__ out){
  int k = blockIdx.x >> 3; int n0 = (blockIdx.x & 7)*64;
  int t = threadIdx.x; int tx = t & 15, ty = t >> 4;
  __shared__ __align__(16) float As[16][68];
  __shared__ __align__(16) float Bs[16][68];
  __shared__ int ehB[64], etB[64];
  __shared__ float red[64][17];
  if (t < 64){
    int n = n0 + t; int b = n >> 7;
    int hi = pairs[n*2+0], ti = pairs[n*2+1];
    ehB[t] = ((b*NE + hi)*KK + k)*DD;
    etB[t] = ((b*NE + ti)*KK + k)*DD;
  }
  __syncthreads();
  int arow = t >> 2, acol = (t & 3)*4;
  int brow = t >> 4, bcol = (t & 15)*4;
  float part[4] = {0.f,0.f,0.f,0.f};
  const float* Bk = B + (size_t)k*DD*DD;
  for (int ptile = 0; ptile < 12; ptile++){
    int p0 = ptile*64;
    float c[4][4] = {};
    for (int dt = 0; dt < 768; dt += 16){
      float4 e4 = *(const float4*)(Eh + ehB[arow] + dt + acol);
      float4 p4 = *(const float4*)(ph + (size_t)(n0+arow)*DD + dt + acol);
      As[acol+0][arow] = fast_tanh(e4.x + p4.x);
      As[acol+1][arow] = fast_tanh(e4.y + p4.y);
      As[acol+2][arow] = fast_tanh(e4.z + p4.z);
      As[acol+3][arow] = fast_tanh(e4.w + p4.w);
      float4 b4 = *(const float4*)(Bk + (size_t)(dt+brow)*DD + p0 + bcol);
      *(float4*)&Bs[brow][bcol] = b4;
      __syncthreads();
      #pragma unroll
      for (int kk2=0;kk2<16;kk2++){
        float4 a4 = *(const float4*)&As[kk2][ty*4];
        float4 bb4 = *(const float4*)&Bs[kk2][tx*4];
        float ar[4]={a4.x,a4.y,a4.z,a4.w}, br[4]={bb4.x,bb4.y,bb4.z,bb4.w};
        #pragma unroll
        for (int i2=0;i2<4;i2++)
          #pragma unroll
          for (int j2=0;j2<4;j2++) c[i2][j2] += ar[i2]*br[j2];
      }
      __syncthreads();
    }
    #pragma unroll
    for (int r=0;r<4;r++){
      int nn = ty*4 + r;
      float4 e4 = *(const float4*)(Et + etB[nn] + p0 + tx*4);
      float4 q4 = *(const float4*)(pt_ + (size_t)(n0+nn)*DD + p0 + tx*4);
      float t0 = fast_tanh(e4.x+q4.x), t1 = fast_tanh(e4.y+q4.y);
      float t2 = fast_tanh(e4.z+q4.z), t3 = fast_tanh(e4.w+q4.w);
      part[r] += c[r][0]*t0 + c[r][1]*t1 + c[r][2]*t2 + c[r][3]*t3;
    }
  }
  #pragma unroll
  for (int r=0;r<4;r++) red[ty*4+r][tx] = part[r];
  __syncthreads();
  if (t < 64){
    float s = 0.f;
    #pragma unroll
    for (int q=0;q<16;q++) s += red[t][q];
    out[(size_t)(n0+t)*KK + k] = s + bias[k];
  }
}

extern "C" void kernel_launch(void* const* d_in, const int* in_sizes, int n_in,
                              void* d_out, int out_size, void* d_ws, size_t ws_size,
                              hipStream_t stream){
  const float* seq      = (const float*)d_in[0];
  const float* att      = (const float*)d_in[1];
  const float* mask     = (const float*)d_in[2];
  const int*   mpos     = (const int*)d_in[3];
  const int*   pairs    = (const int*)d_in[4];
  const float* Wattn    = (const float*)d_in[5];
  const float* battn    = (const float*)d_in[6];
  const float* attn_net = (const float*)d_in[7];
  const float* Wlin     = (const float*)d_in[8];
  const float* blin     = (const float*)d_in[9];
  const float* Wseg     = (const float*)d_in[10];
  const float* bseg     = (const float*)d_in[11];
  const float* Whead    = (const float*)d_in[12];
  const float* bhead    = (const float*)d_in[13];
  const float* Wtail    = (const float*)d_in[14];
  const float* btail    = (const float*)d_in[15];
  const float* bil      = (const float*)d_in[16];
  const float* bilb     = (const float*)d_in[17];
  float* out = (float*)d_out;

  char* ws = (char*)d_ws;
  size_t off = 0;
  auto alloc = [&](size_t nfloats)->float*{
    float* p = (float*)(ws + off);
    off += (nfloats*sizeof(float) + 255) & ~(size_t)255;
    return p;
  };
  float* entity_es = alloc((size_t)MROWS*DD);      // 50 MB
  float* Eh        = alloc((size_t)MROWS*DD);      // 50 MB
  float* Et        = alloc((size_t)MROWS*DD);      // 50 MB
  float* emb       = alloc((size_t)BS*NE*NM*DD);   // 4.1 MB
  float* tbuf      = alloc((size_t)BS*NE*NM*RR);
  float* wsm       = alloc((size_t)BS*NE*NM*KK);
  float* eas       = alloc((size_t)BS*NE*HH*LL);   // 8.3 MB
  float* sl        = alloc((size_t)BS*LL*3);
  float* xb        = alloc((size_t)BS*NE*NE*3);
  float* htss      = alloc((size_t)NPAIR*FF);
  float* ph        = alloc((size_t)NPAIR*DD);
  float* pt        = alloc((size_t)NPAIR*DD);

  k_emb<<<BS*NE*NM, 256, 0, stream>>>(seq, mpos, mask, emb);
  k_score1<<<BS*NE*NM, 256, 0, stream>>>(emb, Wattn, battn, tbuf);
  k_scores<<<BS*NE, 128, 0, stream>>>(tbuf, attn_net, mask, wsm);
  k_entity_as<<<BS*NE*HH, 256, 0, stream>>>(att, mpos, mask, eas);
  k_entity_es<<<BS*NE, 256, 0, stream>>>(emb, wsm, entity_es);
  k_seqlin<<<BS*LL, 256, 0, stream>>>(seq, Wlin, sl);
  k_ht_x<<<BS*NE*NE, 256, 0, stream>>>(eas, sl, blin, xb);
  k_conv_pairs<<<NPAIR, 256, 0, stream>>>(xb, pairs, Wseg, bseg, htss);
  k_pair_proj<<<NPAIR, 256, 0, stream>>>(htss, Whead + 768*768, bhead, ph);
  k_pair_proj<<<NPAIR, 256, 0, stream>>>(htss, Wtail + 768*768, btail, pt);
  int gby = (MROWS + 63)/64;   // 255
  k_gemm768<<<gby*12, 256, 0, stream>>>(entity_es, Whead, Eh, MROWS);
  k_gemm768<<<gby*12, 256, 0, stream>>>(entity_es, Wtail, Et, MROWS);
  k_bilinear<<<KK*8, 256, 0, stream>>>(Eh, Et, ph, pt, bil, bilb, pairs, out);
}

// Round 3
// 1233.525 us; speedup vs baseline: 1.9328x; 1.9328x over previous
//
#include <hip/hip_runtime.h>
#include <hip/hip_bf16.h>

#define BS 4
#define LL 1024
#define DD 768
#define HH 12
#define NE 42
#define NM 8
#define KK 97
#define PPAIR 128
#define FF 256
#define RR 256
#define NPAIR (BS*PPAIR)     // 512
#define MROWS (BS*NE*KK)     // 16296
#define MT 510               // ceil(16296/32)

typedef __attribute__((ext_vector_type(8))) short short8;
typedef __attribute__((ext_vector_type(16))) float float16;

__device__ __forceinline__ float fast_tanh(float x){
  x = fminf(fmaxf(x, -15.f), 15.f);
  float e = __expf(2.f*x);
  return 1.f - 2.f/(e + 1.f);
}
__device__ __forceinline__ unsigned short f2bf(float f){
  unsigned int u = __float_as_uint(f);
  unsigned int r = (u + 0x7FFF + ((u>>16)&1)) >> 16;
  return (unsigned short)r;
}
__device__ __forceinline__ float bf2f(unsigned short u){
  return __uint_as_float(((unsigned int)u)<<16);
}

// ---------------- K1: emb[b,e,m,:] = seq[b,pos,:] * mask ----------------
__global__ void k_emb(const float* __restrict__ seq, const int* __restrict__ mpos,
                      const float* __restrict__ mask, float* __restrict__ emb){
  int idx = blockIdx.x;            // (b*NE+e)*NM+m
  int t = threadIdx.x;
  int b = idx / (NE*NM);
  float mk = mask[idx];
  int pos = mpos[idx] + 1;
  pos = min(max(pos, 0), LL-1);
  const float* src = seq + ((size_t)b*LL + pos)*DD;
  float* dst = emb + (size_t)idx*DD;
  for (int dd = t; dd < DD; dd += 256) dst[dd] = mk * src[dd];
}

// ------------- K2: entity_as[b,e,h,l] = sum_m mask*att[b,h,pos,l]/cnt -------------
__global__ void k_entity_as(const float* __restrict__ att, const int* __restrict__ mpos,
                            const float* __restrict__ mask, float* __restrict__ eas){
  int idx = blockIdx.x;            // (b*NE+e)*HH + hh
  int hh = idx % HH; int be = idx / HH;
  int b = be / NE;
  int t = threadIdx.x;
  float cnt = 0.f;
  for (int m=0;m<NM;m++) cnt += mask[be*NM+m];
  float inv = 1.f / fmaxf(cnt, 1.f);
  float acc[4] = {0.f,0.f,0.f,0.f};
  for (int m=0;m<NM;m++){
    float mk = mask[be*NM+m];
    if (mk != 0.f){
      int pos = min(max(mpos[be*NM+m]+1,0), LL-1);
      const float* row = att + (((size_t)b*HH + hh)*LL + pos)*LL;
      acc[0] += mk*row[t]; acc[1] += mk*row[t+256];
      acc[2] += mk*row[t+512]; acc[3] += mk*row[t+768];
    }
  }
  float* dst = eas + (size_t)idx*LL;
  dst[t]=acc[0]*inv; dst[t+256]=acc[1]*inv; dst[t+512]=acc[2]*inv; dst[t+768]=acc[3]*inv;
}

// ------------- K3a: tbuf[b,e,m,r] = tanh(emb . Wattn[:,r] + battn[r]) -------------
__global__ void k_score1(const float* __restrict__ emb, const float* __restrict__ Wattn,
                         const float* __restrict__ battn, float* __restrict__ tbuf){
  int idx = blockIdx.x; int t = threadIdx.x;  // 256 threads, r = t
  __shared__ float es[DD];
  es[t]       = emb[(size_t)idx*DD + t];
  es[t+256]   = emb[(size_t)idx*DD + t + 256];
  es[t+512]   = emb[(size_t)idx*DD + t + 512];
  __syncthreads();
  float acc = battn[t];
  for (int dd=0; dd<DD; dd++) acc += es[dd]*Wattn[dd*RR + t];
  tbuf[(size_t)idx*RR + t] = fast_tanh(acc);
}

// ------------- K3b: scores + masked softmax over mentions -> w[b,e,m,k] -------------
__global__ void k_scores(const float* __restrict__ tbuf, const float* __restrict__ an,
                         const float* __restrict__ mask, float* __restrict__ w){
  int be = blockIdx.x; int t = threadIdx.x;   // 128 threads
  __shared__ float ts_[NM*RR];                // 8 KB
  __shared__ float an_s[64*98];               // 25 KB chunk of attn_net^T
  for (int i=t; i<NM*RR; i+=128) ts_[i] = tbuf[(size_t)be*NM*RR + i];
  float acc[NM];
  #pragma unroll
  for (int m=0;m<NM;m++) acc[m] = 0.f;
  for (int rc=0; rc<RR; rc+=64){
    __syncthreads();
    for (int i=t; i<KK*64; i+=128){
      int kq = i >> 6, r = i & 63;
      an_s[r*98 + kq] = an[kq*RR + rc + r];
    }
    __syncthreads();
    if (t < KK){
      for (int m=0;m<NM;m++){
        float a = 0.f;
        for (int r=0;r<64;r++) a += ts_[m*RR + rc + r]*an_s[r*98 + t];
        acc[m] += a;
      }
    }
  }
  if (t < KK){
    float s[NM];
    #pragma unroll
    for (int m=0;m<NM;m++){
      float mk = mask[be*NM+m];
      s[m] = acc[m] + (1.f - mk)*(-1e6f);
    }
    float mx = s[0];
    #pragma unroll
    for (int m=1;m<NM;m++) mx = fmaxf(mx, s[m]);
    float sum = 0.f; float e[NM];
    #pragma unroll
    for (int m=0;m<NM;m++){ e[m] = __expf(s[m]-mx); sum += e[m]; }
    float invs = 1.f/sum;
    #pragma unroll
    for (int m=0;m<NM;m++) w[((size_t)be*NM+m)*KK + t] = e[m]*invs;
  }
}

// ------- K4: entity_es -> bf16 in A-fragment order for 32x32x16 MFMA -------
// es_frag[mt][ds][lane][8]: lane = (row&31) + 32*((d>>3)&1), j = d&7, ds = d>>4
__global__ void k_entity_es(const float* __restrict__ emb, const float* __restrict__ w,
                            unsigned short* __restrict__ esf){
  int be = blockIdx.x; int t = threadIdx.x;
  __shared__ float es[NM*DD];    // 24 KB
  __shared__ float ws_[NM*KK];
  for (int i = t; i < NM*DD; i += 256) es[i] = emb[(size_t)be*NM*DD + i];
  for (int i = t; i < NM*KK; i += 256) ws_[i] = w[(size_t)be*NM*KK + i];
  __syncthreads();
  for (int idx = t; idx < KK*96; idx += 256){
    int k = idx % KK, d8 = idx / KK;     // lanes consecutive in k -> broadcast es reads
    int d0 = d8*8;
    float a[8] = {0,0,0,0,0,0,0,0};
    #pragma unroll
    for (int m=0;m<NM;m++){
      float wv = ws_[m*KK + k];
      #pragma unroll
      for (int j=0;j<8;j++) a[j] += wv*es[m*DD + d0 + j];
    }
    int row = be*KK + k;
    int mt = row >> 5, lr = row & 31, ds = d8 >> 1, qq = d8 & 1;
    short8 v;
    #pragma unroll
    for (int j=0;j<8;j++) v[j] = (short)f2bf(a[j]);
    *(short8*)(esf + ((((size_t)mt*48) + ds)*64 + lr + 32*qq)*8) = v;
  }
}

// ------------- K6: seqlin[b,l,c] = seq[b,l,:] . Wlin[:,c] -------------
__global__ void k_seqlin(const float* __restrict__ seq, const float* __restrict__ Wlin,
                         float* __restrict__ sl){
  int bl = blockIdx.x; int t = threadIdx.x;
  const float* row = seq + (size_t)bl*DD;
  float a[3] = {0.f,0.f,0.f};
  for (int dd=t; dd<DD; dd+=256){
    float v = row[dd];
    a[0] += v*Wlin[dd*3+0]; a[1] += v*Wlin[dd*3+1]; a[2] += v*Wlin[dd*3+2];
  }
  __shared__ float red[256];
  float res[3];
  for (int c=0;c<3;c++){
    red[t] = a[c]; __syncthreads();
    for (int off=128; off>0; off>>=1){ if (t<off) red[t]+=red[t+off]; __syncthreads(); }
    res[c] = red[0]; __syncthreads();
  }
  if (t==0){ sl[bl*3+0]=res[0]; sl[bl*3+1]=res[1]; sl[bl*3+2]=res[2]; }
}

// ------------- K5: fused ht einsum + row-normalize + x = htn@seqlin + blin -------------
__global__ void k_ht_x(const float* __restrict__ eas, const float* __restrict__ sl,
                       const float* __restrict__ blin, float* __restrict__ x){
  int idx = blockIdx.x;            // (b*NE+i)*NE + j
  int j = idx % NE; int i = (idx/NE)%NE; int b = idx/(NE*NE);
  int t = threadIdx.x;
  const float* ai = eas + ((size_t)(b*NE+i))*HH*LL;
  const float* aj = eas + ((size_t)(b*NE+j))*HH*LL;
  float v[4];
  #pragma unroll
  for (int it=0; it<4; it++){
    int l = t + it*256;
    float acc=0.f;
    #pragma unroll
    for (int hh2=0; hh2<HH; hh2++) acc += ai[hh2*LL + l]*aj[hh2*LL + l];
    v[it] = acc * (1.f/HH);
  }
  __shared__ float red[256];
  red[t] = v[0]+v[1]+v[2]+v[3]; __syncthreads();
  for (int off=128; off>0; off>>=1){ if (t<off) red[t]+=red[t+off]; __syncthreads(); }
  float inv = 1.f/(red[0] + 1e-5f);
  __syncthreads();
  float xa[3]={0.f,0.f,0.f};
  #pragma unroll
  for (int it=0; it<4; it++){
    int l = t + it*256;
    float wv = v[it]*inv;
    const float* s3 = sl + ((size_t)b*LL + l)*3;
    xa[0]+=wv*s3[0]; xa[1]+=wv*s3[1]; xa[2]+=wv*s3[2];
  }
  for (int c=0;c<3;c++){
    red[t]=xa[c]; __syncthreads();
    for (int off=128; off>0; off>>=1){ if (t<off) red[t]+=red[t+off]; __syncthreads(); }
    if (t==0) x[(size_t)idx*3+c] = red[0] + blin[c];
    __syncthreads();
  }
}

// ------------- K8: 3x3x(3->256) conv + relu at gathered pairs -------------
__global__ void k_conv_pairs(const float* __restrict__ x, const int* __restrict__ pairs,
                             const float* __restrict__ Wseg, const float* __restrict__ bseg,
                             float* __restrict__ htss){
  int n = blockIdx.x; int t = threadIdx.x;   // t = f channel
  int b = n / PPAIR;
  int hi = pairs[n*2+0], ti = pairs[n*2+1];
  __shared__ float xs[27];
  if (t < 27){
    int di = t/9, dj = (t/3)%3, ci = t%3;
    int ii = hi + di - 1, jj = ti + dj - 1;
    float v = 0.f;
    if (ii>=0 && ii<NE && jj>=0 && jj<NE) v = x[(((size_t)b*NE+ii)*NE+jj)*3 + ci];
    xs[t] = v;
  }
  __syncthreads();
  float acc = bseg[t];
  #pragma unroll
  for (int tap=0; tap<27; tap++) acc += xs[tap]*Wseg[tap*FF + t];
  htss[(size_t)n*FF + t] = fmaxf(acc, 0.f);
}

// ------------- K9: pairh[n,:] = htss[n,:] @ W[768:1024,:] + bias -------------
__global__ void k_pair_proj(const float* __restrict__ htss, const float* __restrict__ Wb,
                            const float* __restrict__ bias, float* __restrict__ outp){
  int n = blockIdx.x; int t = threadIdx.x;
  __shared__ float hs_s[FF];
  hs_s[t] = htss[(size_t)n*FF + t];
  __syncthreads();
  float a0 = bias[t], a1 = bias[t+256], a2 = bias[t+512];
  for (int r=0;r<FF;r++){
    float hv = hs_s[r];
    const float* wr = Wb + (size_t)r*DD;
    a0 += hv*wr[t]; a1 += hv*wr[t+256]; a2 += hv*wr[t+512];
  }
  float* dst = outp + (size_t)n*DD;
  dst[t]=a0; dst[t+256]=a1; dst[t+512]=a2;
}

// ------- K-shuffle: fp32 [768(k)][768(n)] -> bf16 B-frag order -------
// dst[ds(48)][nt(24)][lane(64)][j(8)]: lane = (n&31)+32*((k>>3)&1), j=k&7
__global__ void k_wshuffle(const float* __restrict__ src, unsigned short* __restrict__ dst){
  int bi = blockIdx.x;
  int mat = bi / 144; int r = bi % 144;
  int ds = r / 3, ntg = r % 3;
  int t = threadIdx.x;
  size_t mo = (size_t)mat*589824;
  __shared__ float ls[16][260];
  #pragma unroll
  for (int i=0;i<16;i++)
    ls[i][t] = src[mo + ((size_t)(ds*16+i))*768 + ntg*256 + t];
  __syncthreads();
  #pragma unroll
  for (int it=0; it<2; it++){
    int idx = it*256 + t;           // 0..511
    int pt_l = idx >> 6, lane = idx & 63;
    int nl = pt_l*32 + (lane & 31);
    int qq = lane >> 5;
    short8 v;
    #pragma unroll
    for (int j=0;j<8;j++) v[j] = (short)f2bf(ls[qq*8 + j][nl]);
    *(short8*)(dst + mo + (((size_t)ds*24 + ntg*8 + pt_l)*64 + lane)*8) = v;
  }
}

// ------------- K10: C_bf16[M,768] = A_frag @ B_frag (32x32x16 MFMA, LDS-free) -------------
__global__ __launch_bounds__(256) void k_gemm_frag(const unsigned short* __restrict__ Af,
    const unsigned short* __restrict__ Bf, unsigned short* __restrict__ C){
  int mt = blockIdx.x / 6, ntg = blockIdx.x % 6;
  int t = threadIdx.x; int w = t >> 6; int lane = t & 63;
  int nt = ntg*4 + w;
  float16 acc = (float16)(0.0f);
  const unsigned short* ap = Af + (((size_t)mt*48)*64 + lane)*8;
  const unsigned short* bp = Bf + (((size_t)nt)*64 + lane)*8;
  #pragma unroll 4
  for (int ds=0; ds<48; ds++){
    short8 a = *(const short8*)(ap + (size_t)ds*512);
    short8 b = *(const short8*)(bp + (size_t)ds*24*512);
    acc = __builtin_amdgcn_mfma_f32_32x32x16_bf16(a, b, acc, 0, 0, 0);
  }
  int col = nt*32 + (lane & 31);
  int aq = lane >> 5;
  #pragma unroll
  for (int rI=0;rI<16;rI++){
    int row = mt*32 + (rI&3) + 8*(rI>>2) + 4*aq;
    C[(size_t)row*768 + col] = f2bf(acc[rI]);
  }
}

// ------------- K11: bilinear via MFMA -------------
// block = (k, 64-row tile). wave w: wr=w&1 (row half), wc=w>>1 (p-tile parity).
// Each (wr,*) pair of waves covers complementary p-halves -> combine via LDS.
__global__ __launch_bounds__(256,2) void k_bilinear_mfma(
    const unsigned short* __restrict__ Ehb, const unsigned short* __restrict__ Etb,
    const float* __restrict__ ph, const float* __restrict__ pt_,
    const unsigned short* __restrict__ Bfrag, const float* __restrict__ bias,
    const int* __restrict__ pairs, float* __restrict__ out){
  int k = blockIdx.x >> 3; int n0 = (blockIdx.x & 7)*64;
  int t = threadIdx.x; int w = t >> 6; int lane = t & 63;
  int wr = w & 1, wc = w >> 1;
  __shared__ int ehB[64], etB[64];
  __shared__ float redbuf[2][2][32];   // [wr][wc][row]
  if (t < 64){
    int n = n0 + t; int b = n >> 7;
    ehB[t] = ((b*NE + pairs[n*2+0])*KK + k)*DD;
    etB[t] = ((b*NE + pairs[n*2+1])*KK + k)*DD;
  }
  __syncthreads();
  int arow = wr*32 + (lane & 31);
  int aq = lane >> 5;
  const unsigned short* ehp = Ehb + ehB[arow];
  const float* php = ph + (size_t)(n0 + arow)*DD;
  const unsigned short* bb = Bfrag + (size_t)k*589824 + (size_t)lane*8;
  float16 acc[12];
  #pragma unroll
  for (int i=0;i<12;i++) acc[i] = (float16)(0.0f);
  for (int ds=0; ds<48; ds++){
    int d0 = ds*16 + aq*8;
    short8 ev = *(const short8*)(ehp + d0);
    float4 p0 = *(const float4*)(php + d0);
    float4 p1 = *(const float4*)(php + d0 + 4);
    float pf[8] = {p0.x,p0.y,p0.z,p0.w,p1.x,p1.y,p1.z,p1.w};
    short8 afrag;
    #pragma unroll
    for (int j=0;j<8;j++)
      afrag[j] = (short)f2bf(fast_tanh(bf2f((unsigned short)ev[j]) + pf[j]));
    const unsigned short* bds = bb + (size_t)ds*24*512;
    #pragma unroll
    for (int p2=0; p2<12; p2++){
      short8 bfr = *(const short8*)(bds + (size_t)(p2*2 + wc)*512);
      acc[p2] = __builtin_amdgcn_mfma_f32_32x32x16_bf16(afrag, bfr, acc[p2], 0, 0, 0);
    }
  }
  // epilogue: s[row] = sum_{p in this wave's half} U[row,p]*tanh(Et+pt)[row,p]
  #pragma unroll
  for (int rI=0;rI<16;rI++){
    int row = (rI&3) + 8*(rI>>2) + 4*aq;      // 0..31 within wave's half
    int nloc = wr*32 + row;
    int eb = etB[nloc];
    const float* ptp = pt_ + (size_t)(n0 + nloc)*DD;
    float s = 0.f;
    #pragma unroll
    for (int p2=0; p2<12; p2++){
      int col = (p2*2 + wc)*32 + (lane & 31);
      float tv = fast_tanh(bf2f(Etb[eb + col]) + ptp[col]);
      s += acc[p2][rI]*tv;
    }
    s += __shfl_xor(s, 1);  s += __shfl_xor(s, 2);
    s += __shfl_xor(s, 4);  s += __shfl_xor(s, 8);
    s += __shfl_xor(s, 16);
    if ((lane & 31) == 0) redbuf[wr][wc][row] = s;
  }
  __syncthreads();
  if (t < 64){
    int wrr = t >> 5, r = t & 31;
    out[(size_t)(n0 + t)*KK + k] = redbuf[wrr][0][r] + redbuf[wrr][1][r] + bias[k];
  }
}

extern "C" void kernel_launch(void* const* d_in, const int* in_sizes, int n_in,
                              void* d_out, int out_size, void* d_ws, size_t ws_size,
                              hipStream_t stream){
  const float* seq      = (const float*)d_in[0];
  const float* att      = (const float*)d_in[1];
  const float* mask     = (const float*)d_in[2];
  const int*   mpos     = (const int*)d_in[3];
  const int*   pairs    = (const int*)d_in[4];
  const float* Wattn    = (const float*)d_in[5];
  const float* battn    = (const float*)d_in[6];
  const float* attn_net = (const float*)d_in[7];
  const float* Wlin     = (const float*)d_in[8];
  const float* blin     = (const float*)d_in[9];
  const float* Wseg     = (const float*)d_in[10];
  const float* bseg     = (const float*)d_in[11];
  const float* Whead    = (const float*)d_in[12];
  const float* bhead    = (const float*)d_in[13];
  const float* Wtail    = (const float*)d_in[14];
  const float* btail    = (const float*)d_in[15];
  const float* bil      = (const float*)d_in[16];
  const float* bilb     = (const float*)d_in[17];
  float* out = (float*)d_out;

  char* ws = (char*)d_ws;
  size_t off = 0;
  auto allocB = [&](size_t nbytes)->char*{
    char* p = ws + off;
    off += (nbytes + 255) & ~(size_t)255;
    return p;
  };
  float* emb  = (float*)allocB((size_t)BS*NE*NM*DD*4);
  float* tbuf = (float*)allocB((size_t)BS*NE*NM*RR*4);
  float* wsm  = (float*)allocB((size_t)BS*NE*NM*KK*4);
  float* eas  = (float*)allocB((size_t)BS*NE*HH*LL*4);
  float* sl   = (float*)allocB((size_t)BS*LL*3*4);
  float* xb   = (float*)allocB((size_t)BS*NE*NE*3*4);
  float* htss = (float*)allocB((size_t)NPAIR*FF*4);
  float* phb  = (float*)allocB((size_t)NPAIR*DD*4);
  float* ptb  = (float*)allocB((size_t)NPAIR*DD*4);
  unsigned short* esf    = (unsigned short*)allocB((size_t)MT*48*64*8*2);   // 25 MB
  unsigned short* WheadF = (unsigned short*)allocB((size_t)589824*2);
  unsigned short* WtailF = (unsigned short*)allocB((size_t)589824*2);
  unsigned short* BF     = (unsigned short*)allocB((size_t)KK*589824*2);    // 114.4 MB
  unsigned short* Ehb    = (unsigned short*)allocB((size_t)MT*32*768*2);    // 25 MB
  unsigned short* Etb    = (unsigned short*)allocB((size_t)MT*32*768*2);    // 25 MB

  k_emb<<<BS*NE*NM, 256, 0, stream>>>(seq, mpos, mask, emb);
  k_score1<<<BS*NE*NM, 256, 0, stream>>>(emb, Wattn, battn, tbuf);
  k_scores<<<BS*NE, 128, 0, stream>>>(tbuf, attn_net, mask, wsm);
  k_entity_as<<<BS*NE*HH, 256, 0, stream>>>(att, mpos, mask, eas);
  k_entity_es<<<BS*NE, 256, 0, stream>>>(emb, wsm, esf);
  k_seqlin<<<BS*LL, 256, 0, stream>>>(seq, Wlin, sl);
  k_ht_x<<<BS*NE*NE, 256, 0, stream>>>(eas, sl, blin, xb);
  k_conv_pairs<<<NPAIR, 256, 0, stream>>>(xb, pairs, Wseg, bseg, htss);
  k_pair_proj<<<NPAIR, 256, 0, stream>>>(htss, Whead + 768*768, bhead, phb);
  k_pair_proj<<<NPAIR, 256, 0, stream>>>(htss, Wtail + 768*768, btail, ptb);
  k_wshuffle<<<144, 256, 0, stream>>>(Whead, WheadF);
  k_wshuffle<<<144, 256, 0, stream>>>(Wtail, WtailF);
  k_wshuffle<<<KK*144, 256, 0, stream>>>(bil, BF);
  k_gemm_frag<<<MT*6, 256, 0, stream>>>(esf, WheadF, Ehb);
  k_gemm_frag<<<MT*6, 256, 0, stream>>>(esf, WtailF, Etb);
  k_bilinear_mfma<<<KK*8, 256, 0, stream>>>(Ehb, Etb, phb, ptb, BF, bilb, pairs, out);
}